// Round 2
// baseline (238.395 us; speedup 1.0000x reference)
//
#include <hip/hip_runtime.h>
#include <hip/hip_bf16.h>

// minLSTM: pre = x @ W^T + b (M=32768, N=1536, K=512), log-space gates,
// chunked log-space scan over L=4096 per (n,h), out = exp(log_h).
// ALL log-domain values are in LOG2 units (v_exp/v_log are base-2 native).
// Gate math: sigma-sum identity (3 exp + 4 log per position).
// x is NOT pre-converted: gemm stages A directly from the original input
// (fp32 path: global->reg->cvt_pk_bf16->ds_write into the same swizzled
// layout; bf16 path: global_load_lds direct). Grid is (by, bx) so all 8
// column-blocks sharing an A-tile land on the same XCD (linear%8 == by%8).

#define H_DIM 512
#define LSEQ 4096
#define NBATCH 8
#define M_TOTAL (NBATCH * LSEQ)  // 32768

#define BM 128
#define BK 64

#define CS 128
#define NC 32            // LSEQ / CS

typedef __attribute__((ext_vector_type(8))) short short8;
typedef __attribute__((ext_vector_type(4))) float floatx4;
typedef __attribute__((ext_vector_type(4))) float float4v;
typedef _Float16 h2 __attribute__((ext_vector_type(2)));
typedef _Float16 h4 __attribute__((ext_vector_type(4)));
typedef __attribute__((ext_vector_type(2))) float float2v;

#define NEG_BIG (-1.0e30f)
#define C_LOG2E 1.4426950408889634f
#define LOG2_HX0 (-19.931568569324174f)   // log2(1e-6)

__device__ __forceinline__ float exp2_hw(float x) {
#if __has_builtin(__builtin_amdgcn_exp2f)
    return __builtin_amdgcn_exp2f(x);     // v_exp_f32
#else
    return exp2f(x);
#endif
}

__device__ __forceinline__ float log2_hw(float x) {
#if __has_builtin(__builtin_amdgcn_logf)
    return __builtin_amdgcn_logf(x);      // v_log_f32 (base-2)
#else
    return log2f(x);
#endif
}

// log2(2^p + 2^q), robust for -inf-ish inputs
__device__ __forceinline__ float logaddexp2_f(float p, float q) {
    float m = fmaxf(p, q);
    float d = -fabsf(p - q);
    return m + log2_hw(1.0f + exp2_hw(d));
}

__device__ __forceinline__ float bf16u_to_f(unsigned short u) {
    unsigned int w = ((unsigned int)u) << 16;
    float f;
    __builtin_memcpy(&f, &w, 4);
    return f;
}

__device__ __forceinline__ unsigned short f_to_bf16u(float f) {
    __hip_bfloat16 h = __float2bfloat16(f);
    unsigned short u;
    __builtin_memcpy(&u, &h, 2);
    return u;
}

// packed f32x2 -> bf16x2 (RNE), single HW instr on gfx950
__device__ __forceinline__ unsigned int cvtpk_bf16(float lo, float hi) {
    unsigned int r;
    asm("v_cvt_pk_bf16_f32 %0, %1, %2" : "=v"(r) : "v"(lo), "v"(hi));
    return r;
}

__device__ __forceinline__ void gload_lds16(const void* g, void* l) {
    __builtin_amdgcn_global_load_lds(
        (const __attribute__((address_space(1))) unsigned int*)g,
        (__attribute__((address_space(3))) unsigned int*)l, 16, 0, 0);
}

// ---------------------------------------------------------------------------
// Kernel 0: dtype detect (single block) + bias -> f32.
// fp32 data: low u16 halves uniform -> bf16-NaN exponent P=1/256,
// E[hits in 16384] = 64; bf16 N(0,1) data: 0 hits.
// ---------------------------------------------------------------------------
__global__ void detect_and_bias(const unsigned short* __restrict__ xu,
                                const void* __restrict__ bsrc,
                                int* __restrict__ flag,
                                float* __restrict__ bdst) {
    __shared__ int cnt;
    if (threadIdx.x == 0) cnt = 0;
    __syncthreads();
    int local = 0;
    for (int i = threadIdx.x; i < 16384; i += 256) {
        unsigned short u = xu[i];
        if (((u >> 7) & 0xFF) == 0xFF) local++;
    }
    if (local) atomicAdd(&cnt, local);
    __syncthreads();
    int f = (cnt > 8) ? 1 : 0;
    if (threadIdx.x == 0) flag[0] = f;
    for (int i = threadIdx.x; i < 3 * H_DIM; i += 256)
        bdst[i] = f ? ((const float*)bsrc)[i]
                    : bf16u_to_f(((const unsigned short*)bsrc)[i]);
}

// ---------------------------------------------------------------------------
// Kernel 0b: normalize W to bf16 (x no longer pre-converted).
// W: 1536*512 = 786432 elems = 384 blocks * 256 threads * 8.
// ---------------------------------------------------------------------------
__global__ __launch_bounds__(256)
void convert_w(const void* __restrict__ W, unsigned short* __restrict__ Wc,
               const int* __restrict__ flag) {
    const int i = (blockIdx.x * 256 + threadIdx.x) * 8;
    if (*flag) {
        const float4v* s4 = (const float4v*)((const float*)W + i);
        float4v a = s4[0], b = s4[1];
        short8 v;
        v[0] = (short)f_to_bf16u(a[0]); v[1] = (short)f_to_bf16u(a[1]);
        v[2] = (short)f_to_bf16u(a[2]); v[3] = (short)f_to_bf16u(a[3]);
        v[4] = (short)f_to_bf16u(b[0]); v[5] = (short)f_to_bf16u(b[1]);
        v[6] = (short)f_to_bf16u(b[2]); v[7] = (short)f_to_bf16u(b[3]);
        *(short8*)&Wc[i] = v;
    } else {
        *(short8*)&Wc[i] = *(const short8*)&((const short*)W)[i];
    }
}

// ---------------------------------------------------------------------------
// Kernel 1: GEMM + gate math + fused scan summaries.
// Block 256 = 4 waves (2x2). A staged from original x (dual dtype path),
// B staged via global_load_lds width-16 from Wc. LDS XOR swizzle
// (verified: conflicts ~0). Tail: wave w scans its 32-t sub-segment ->
// Asub/Bsub (global) + LDS; wave 0 folds 4 -> Asum/Bval.
// Grid (256, 8): by = blockIdx.x so same-by col-blocks share an XCD L2.
// ---------------------------------------------------------------------------
__global__ __launch_bounds__(256, 3)
void gemm_gates(const void* __restrict__ x,
                const unsigned short* __restrict__ W,
                const float* __restrict__ bias,
                const int* __restrict__ flag,
                h2* __restrict__ plv,
                float* __restrict__ Asum, float* __restrict__ Bval,
                float* __restrict__ Asub, float* __restrict__ Bsub) {
    __shared__ __align__(16) char ldsbuf[40960];
    short* Alds = (short*)ldsbuf;              // 16 KB during K-loop
    short* Blds = (short*)(ldsbuf + 16384);    // 24 KB during K-loop
    h2* sc = (h2*)ldsbuf;                      // 32 KB after K-loop
    float* sa = (float*)(ldsbuf + 32768);      // 1 KB sub-summary A
    float* sb = sa + 256;                      // 1 KB sub-summary B

    const int by = blockIdx.x;             // row block 0..255 (XCD = by%8)
    const int bx = blockIdx.y;             // col block 0..7 (64 cols/gate)
    const int tid = threadIdx.x;
    const int lane = tid & 63;
    const int w = tid >> 6;
    const int wr = (w >> 1) * 64;
    const int wc2 = w & 1;
    const int l8 = lane >> 3, s8 = lane & 7;
    const int sg = s8 ^ l8;                // swizzled global seg for staging
    const int fr = lane & 15;
    const int q = lane >> 4;

    const int R0 = by * BM;
    const int f32in = *flag;

    floatx4 acc[4][6];
    #pragma unroll
    for (int i = 0; i < 4; i++)
        #pragma unroll
        for (int j = 0; j < 6; j++)
            acc[i][j] = (floatx4){0.f, 0.f, 0.f, 0.f};

    const float* xf = (const float*)x;
    const short* xh = (const short*)x;
    const short* wg = (const short*)W;

    for (int k0 = 0; k0 < H_DIM; k0 += BK) {
        __syncthreads();
        if (f32in) {
            // global fp32 -> reg -> cvt_pk bf16 -> ds_write_b128.
            // Same LDS image as gload_lds path: dest = chunk base + lane*16B,
            // data = global seg (s8 ^ l8) of row c*8+l8.
            float4v va[4][2];
            #pragma unroll
            for (int i = 0; i < 4; i++) {
                int c = w * 4 + i;
                const float* g = xf + (size_t)(R0 + c * 8 + l8) * H_DIM + k0 + sg * 8;
                va[i][0] = *(const float4v*)g;
                va[i][1] = *(const float4v*)(g + 4);
            }
            #pragma unroll
            for (int i = 0; i < 4; i++) {
                int c = w * 4 + i;
                union { short8 s; unsigned int u[4]; } pkv;
                pkv.u[0] = cvtpk_bf16(va[i][0][0], va[i][0][1]);
                pkv.u[1] = cvtpk_bf16(va[i][0][2], va[i][0][3]);
                pkv.u[2] = cvtpk_bf16(va[i][1][0], va[i][1][1]);
                pkv.u[3] = cvtpk_bf16(va[i][1][2], va[i][1][3]);
                *(short8*)&Alds[c * 512 + lane * 8] = pkv.s;
            }
        } else {
            #pragma unroll
            for (int i = 0; i < 4; i++) {
                int c = w * 4 + i;
                const short* g = xh + (size_t)(R0 + c * 8 + l8) * H_DIM + k0 + sg * 8;
                gload_lds16(g, &Alds[c * 512]);
            }
        }
        #pragma unroll
        for (int i = 0; i < 6; i++) {
            int c = w * 6 + i;
            int br = c * 8 + l8;
            int wrow = (br >> 6) * H_DIM + bx * 64 + (br & 63);
            const short* g = wg + (size_t)wrow * H_DIM + k0 + sg * 8;
            gload_lds16(g, &Blds[c * 512]);
        }
        __syncthreads();

        #pragma unroll
        for (int ks = 0; ks < 2; ks++) {
            const int s = ks * 4 + q;
            short8 af[4], bf[6];
            #pragma unroll
            for (int mt = 0; mt < 4; mt++) {
                int ar = wr + mt * 16 + fr;
                af[mt] = *(const short8*)&Alds[ar * BK + ((s ^ (ar & 7)) << 3)];
            }
            #pragma unroll
            for (int j = 0; j < 6; j++) {
                int nt = (j >> 1) * 4 + wc2 * 2 + (j & 1);
                int brr = nt * 16 + fr;
                bf[j] = *(const short8*)&Blds[brr * BK + ((s ^ (brr & 7)) << 3)];
            }
            #pragma unroll
            for (int mt = 0; mt < 4; mt++)
                #pragma unroll
                for (int j = 0; j < 6; j++)
                    acc[mt][j] = __builtin_amdgcn_mfma_f32_16x16x32_bf16(
                        af[mt], bf[j], acc[mt][j], 0, 0, 0);
        }
    }

    __syncthreads();   // staging LDS dead; reuse as sc

    // Epilogue: C/D layout col=lane&15, row=quad*4+reg [m89/m91].
    // sigma-sum form, all in log2 units:
    //   af=1+2^(-f*log2e), ai=1+2^(-i*log2e), s=af+ai
    //   lf = log2(ai)-log2(s); lv = log2(af)-log2(s) + lg
    //   lg = h>=0 ? log2(h+0.5) : -log2(1+2^(-h*log2e))  (argument-select)
    const int rowb = R0 + wr + q * 4;
    const int tloc0 = wr + q * 4;
    #pragma unroll
    for (int jj = 0; jj < 2; jj++) {
        int hl = wc2 * 32 + jj * 16 + fr;
        int hcol = bx * 64 + hl;
        float bfv = bias[hcol];
        float biv = bias[H_DIM + hcol];
        float bhv = bias[2 * H_DIM + hcol];
        float bf2 = -bfv * C_LOG2E;        // fold bias into exp arg via fma
        float bi2 = -biv * C_LOG2E;
        #pragma unroll
        for (int mt = 0; mt < 4; mt++) {
            #pragma unroll
            for (int r = 0; r < 4; r++) {
                float ef = exp2_hw(fminf(fmaf(acc[mt][jj][r], -C_LOG2E, bf2), 126.0f));
                float ei = exp2_hw(fminf(fmaf(acc[mt][2 + jj][r], -C_LOG2E, bi2), 126.0f));
                float hp = acc[mt][4 + jj][r] + bhv;
                float eh = exp2_hw(fminf(-hp * C_LOG2E, 126.0f));
                float afv = 1.0f + ef, aiv = 1.0f + ei;
                float sfi = afv + aiv;
                float ls = log2_hw(sfi);
                float lf = log2_hw(aiv) - ls;                  // log2 f'
                float marg = (hp >= 0.0f) ? (hp + 0.5f) : (1.0f + eh);
                float lm = log2_hw(marg);
                float lg = (hp >= 0.0f) ? lm : -lm;            // log2 g
                float lv = (log2_hw(afv) - ls) + lg;           // log2 (i' g)
                int row = rowb + mt * 16 + r;
                h2 pk;
                pk[0] = (_Float16)lf;
                pk[1] = (_Float16)lv;
                plv[(size_t)row * H_DIM + hcol] = pk;
                sc[(tloc0 + mt * 16 + r) * 64 + hl] = pk;
            }
        }
    }

    __syncthreads();

    const int n = by >> 5, c = by & 31;
    // Wave w scans t in [w*32, w*32+32) for col=lane; publish sub-summary.
    {
        float a = 0.f, bacc = NEG_BIG;
        const int t0 = w * 32;
        #pragma unroll 4
        for (int t = t0; t < t0 + 32; t++) {
            h2 p = sc[t * 64 + lane];
            float f = (float)p[0];
            bacc = logaddexp2_f(f + bacc, (float)p[1]);
            a += f;
        }
        sa[w * 64 + lane] = a;
        sb[w * 64 + lane] = bacc;
        size_t o = (((size_t)n * NC + c) * 4 + w) * H_DIM + bx * 64 + lane;
        Asub[o] = a;
        Bsub[o] = bacc;
    }
    __syncthreads();

    if (w == 0) {
        float a = sa[lane], b = sb[lane];
        #pragma unroll
        for (int s = 1; s < 4; s++) {
            float as = sa[s * 64 + lane], bs = sb[s * 64 + lane];
            b = logaddexp2_f(as + b, bs);
            a += as;
        }
        size_t o = ((size_t)n * NC + c) * H_DIM + bx * 64 + lane;
        Asum[o] = a;
        Bval[o] = b;
    }
}

// ---------------------------------------------------------------------------
// Kernel 2: sub-chunk replay. Block (cc, n): c = cc>>2, s = cc&3.
// Carry = fold of c chunk summaries + s sub-summaries (<=34 steps), then
// replay 32 timesteps. 2 h-cols/thread, 8B loads. grid (128, 8) = 1024 blocks.
// Carry-fold loads batched 4-wide to hide L2 latency on the runtime loop.
// ---------------------------------------------------------------------------
__global__ __launch_bounds__(256)
void scan_apply(const h2* __restrict__ plv,
                const float* __restrict__ Asum, const float* __restrict__ Bval,
                const float* __restrict__ Asub, const float* __restrict__ Bsub,
                void* __restrict__ outv, const int* __restrict__ flag) {
    const int cc = blockIdx.x;          // 0..127
    const int n = blockIdx.y;
    const int c = cc >> 2, s = cc & 3;
    const int h0 = threadIdx.x * 2;
    const int f32out = *flag;

    float r0 = LOG2_HX0;                // log2(1e-6)
    float r1 = r0;
    size_t so = (size_t)n * NC * H_DIM + h0;
    int cp = 0;
    for (; cp + 4 <= c; cp += 4) {
        float2v A0 = *(const float2v*)&Asum[so + (size_t)(cp + 0) * H_DIM];
        float2v B0 = *(const float2v*)&Bval[so + (size_t)(cp + 0) * H_DIM];
        float2v A1 = *(const float2v*)&Asum[so + (size_t)(cp + 1) * H_DIM];
        float2v B1 = *(const float2v*)&Bval[so + (size_t)(cp + 1) * H_DIM];
        float2v A2 = *(const float2v*)&Asum[so + (size_t)(cp + 2) * H_DIM];
        float2v B2 = *(const float2v*)&Bval[so + (size_t)(cp + 2) * H_DIM];
        float2v A3 = *(const float2v*)&Asum[so + (size_t)(cp + 3) * H_DIM];
        float2v B3 = *(const float2v*)&Bval[so + (size_t)(cp + 3) * H_DIM];
        r0 = logaddexp2_f(A0[0] + r0, B0[0]); r1 = logaddexp2_f(A0[1] + r1, B0[1]);
        r0 = logaddexp2_f(A1[0] + r0, B1[0]); r1 = logaddexp2_f(A1[1] + r1, B1[1]);
        r0 = logaddexp2_f(A2[0] + r0, B2[0]); r1 = logaddexp2_f(A2[1] + r1, B2[1]);
        r0 = logaddexp2_f(A3[0] + r0, B3[0]); r1 = logaddexp2_f(A3[1] + r1, B3[1]);
    }
    for (; cp < c; cp++) {
        float2v A = *(const float2v*)&Asum[so + (size_t)cp * H_DIM];
        float2v B = *(const float2v*)&Bval[so + (size_t)cp * H_DIM];
        r0 = logaddexp2_f(A[0] + r0, B[0]);
        r1 = logaddexp2_f(A[1] + r1, B[1]);
    }
    size_t sub = (((size_t)n * NC + c) * 4) * H_DIM + h0;
    for (int sp = 0; sp < s; sp++) {
        float2v A = *(const float2v*)&Asub[sub + (size_t)sp * H_DIM];
        float2v B = *(const float2v*)&Bsub[sub + (size_t)sp * H_DIM];
        r0 = logaddexp2_f(A[0] + r0, B[0]);
        r1 = logaddexp2_f(A[1] + r1, B[1]);
    }

    size_t base = ((size_t)n * LSEQ + (size_t)c * CS + s * 32) * H_DIM + h0;
    if (f32out) {
        float* of = (float*)outv;
        #pragma unroll 4
        for (int t = 0; t < 32; t++) {
            size_t idx = base + (size_t)t * H_DIM;
            h4 p = *(const h4*)&plv[idx];          // (lf0, lv0, lf1, lv1)
            r0 = logaddexp2_f((float)p[0] + r0, (float)p[1]);
            r1 = logaddexp2_f((float)p[2] + r1, (float)p[3]);
            float2v o2 = {exp2_hw(r0), exp2_hw(r1)};
            *(float2v*)&of[idx] = o2;
        }
    } else {
        unsigned int* ob32 = (unsigned int*)outv;
        #pragma unroll 4
        for (int t = 0; t < 32; t++) {
            size_t idx = base + (size_t)t * H_DIM;
            h4 p = *(const h4*)&plv[idx];
            r0 = logaddexp2_f((float)p[0] + r0, (float)p[1]);
            r1 = logaddexp2_f((float)p[2] + r1, (float)p[3]);
            unsigned int pk = ((unsigned int)f_to_bf16u(exp2_hw(r1)) << 16)
                            | f_to_bf16u(exp2_hw(r0));
            ob32[idx >> 1] = pk;
        }
    }
}

extern "C" void kernel_launch(void* const* d_in, const int* in_sizes, int n_in,
                              void* d_out, int out_size, void* d_ws, size_t ws_size,
                              hipStream_t stream) {
    const void* x = d_in[0];
    const void* W = d_in[1];
    const void* b = d_in[2];

    char* wsb = (char*)d_ws;
    int* flag            = (int*)wsb;                          // 16 B
    float* bconv         = (float*)(wsb + 16);                 // 6 KB
    unsigned short* Wc   = (unsigned short*)(wsb + 16384 + 33554432);  // 1.5 MB
    h2* plv              = (h2*)(wsb + 36700160);              // 64 MB packed (lf,lv)
    float* Asum          = (float*)(wsb + 103809024);          // 512 KB
    float* Bval          = (float*)(wsb + 104333312);          // 512 KB
    float* Asub          = (float*)(wsb + 104857600);          // 2 MB
    float* Bsub          = (float*)(wsb + 106954752);          // 2 MB

    detect_and_bias<<<1, 256, 0, stream>>>((const unsigned short*)x, b, flag, bconv);
    convert_w<<<384, 256, 0, stream>>>(W, Wc, flag);

    dim3 g1(M_TOTAL / BM, H_DIM / 64);   // (256, 8): by on x for XCD share
    gemm_gates<<<g1, 256, 0, stream>>>(x, Wc, bconv, flag, plv, Asum, Bval, Asub, Bsub);

    dim3 g2(NC * 4, NBATCH);             // (128, 8)
    scan_apply<<<g2, 256, 0, stream>>>(plv, Asum, Bval, Asub, Bsub, d_out, flag);
}

// Round 3
// 230.718 us; speedup vs baseline: 1.0333x; 1.0333x over previous
//
#include <hip/hip_runtime.h>
#include <hip/hip_bf16.h>

// minLSTM: pre = x @ W^T + b (M=32768, N=1536, K=512), log-space gates,
// chunked log-space scan over L=4096 per (n,h), out = exp(log_h).
// ALL log-domain values are in LOG2 units (v_exp/v_log are base-2 native).
// Gate math: sigma-sum identity (3 exp + 4 log per position).
// x is NOT pre-converted: gemm stages A directly from the original input.
// fp32 path: ASYNC-SPLIT reg staging (T14) — issue global loads for step
// k+1 at the top of step k's compute phase; cvt_pk+ds_write consume them
// one full compute phase later, hiding HBM latency off the critical path.
// bf16 path: global_load_lds direct. Grid is (by, bx) so all 8 col-blocks
// sharing an A-tile land on the same XCD (linear%8 == by%8).

#define H_DIM 512
#define LSEQ 4096
#define NBATCH 8
#define M_TOTAL (NBATCH * LSEQ)  // 32768

#define BM 128
#define BK 64

#define CS 128
#define NC 32            // LSEQ / CS

typedef __attribute__((ext_vector_type(8))) short short8;
typedef __attribute__((ext_vector_type(4))) float floatx4;
typedef __attribute__((ext_vector_type(4))) float float4v;
typedef _Float16 h2 __attribute__((ext_vector_type(2)));
typedef _Float16 h4 __attribute__((ext_vector_type(4)));
typedef __attribute__((ext_vector_type(2))) float float2v;

#define NEG_BIG (-1.0e30f)
#define C_LOG2E 1.4426950408889634f
#define LOG2_HX0 (-19.931568569324174f)   // log2(1e-6)

__device__ __forceinline__ float exp2_hw(float x) {
#if __has_builtin(__builtin_amdgcn_exp2f)
    return __builtin_amdgcn_exp2f(x);     // v_exp_f32
#else
    return exp2f(x);
#endif
}

__device__ __forceinline__ float log2_hw(float x) {
#if __has_builtin(__builtin_amdgcn_logf)
    return __builtin_amdgcn_logf(x);      // v_log_f32 (base-2)
#else
    return log2f(x);
#endif
}

// log2(2^p + 2^q), robust for -inf-ish inputs
__device__ __forceinline__ float logaddexp2_f(float p, float q) {
    float m = fmaxf(p, q);
    float d = -fabsf(p - q);
    return m + log2_hw(1.0f + exp2_hw(d));
}

__device__ __forceinline__ float bf16u_to_f(unsigned short u) {
    unsigned int w = ((unsigned int)u) << 16;
    float f;
    __builtin_memcpy(&f, &w, 4);
    return f;
}

__device__ __forceinline__ unsigned short f_to_bf16u(float f) {
    __hip_bfloat16 h = __float2bfloat16(f);
    unsigned short u;
    __builtin_memcpy(&u, &h, 2);
    return u;
}

// packed f32x2 -> bf16x2 (RNE), single HW instr on gfx950
__device__ __forceinline__ unsigned int cvtpk_bf16(float lo, float hi) {
    unsigned int r;
    asm("v_cvt_pk_bf16_f32 %0, %1, %2" : "=v"(r) : "v"(lo), "v"(hi));
    return r;
}

__device__ __forceinline__ void gload_lds16(const void* g, void* l) {
    __builtin_amdgcn_global_load_lds(
        (const __attribute__((address_space(1))) unsigned int*)g,
        (__attribute__((address_space(3))) unsigned int*)l, 16, 0, 0);
}

// ---------------------------------------------------------------------------
// Kernel 0: dtype detect (single block) + bias -> f32.
// fp32 data: low u16 halves uniform -> bf16-NaN exponent P=1/256,
// E[hits in 16384] = 64; bf16 N(0,1) data: 0 hits.
// ---------------------------------------------------------------------------
__global__ void detect_and_bias(const unsigned short* __restrict__ xu,
                                const void* __restrict__ bsrc,
                                int* __restrict__ flag,
                                float* __restrict__ bdst) {
    __shared__ int cnt;
    if (threadIdx.x == 0) cnt = 0;
    __syncthreads();
    int local = 0;
    for (int i = threadIdx.x; i < 16384; i += 256) {
        unsigned short u = xu[i];
        if (((u >> 7) & 0xFF) == 0xFF) local++;
    }
    if (local) atomicAdd(&cnt, local);
    __syncthreads();
    int f = (cnt > 8) ? 1 : 0;
    if (threadIdx.x == 0) flag[0] = f;
    for (int i = threadIdx.x; i < 3 * H_DIM; i += 256)
        bdst[i] = f ? ((const float*)bsrc)[i]
                    : bf16u_to_f(((const unsigned short*)bsrc)[i]);
}

// ---------------------------------------------------------------------------
// Kernel 0b: normalize W to bf16 (x no longer pre-converted).
// W: 1536*512 = 786432 elems = 384 blocks * 256 threads * 8.
// ---------------------------------------------------------------------------
__global__ __launch_bounds__(256)
void convert_w(const void* __restrict__ W, unsigned short* __restrict__ Wc,
               const int* __restrict__ flag) {
    const int i = (blockIdx.x * 256 + threadIdx.x) * 8;
    if (*flag) {
        const float4v* s4 = (const float4v*)((const float*)W + i);
        float4v a = s4[0], b = s4[1];
        short8 v;
        v[0] = (short)f_to_bf16u(a[0]); v[1] = (short)f_to_bf16u(a[1]);
        v[2] = (short)f_to_bf16u(a[2]); v[3] = (short)f_to_bf16u(a[3]);
        v[4] = (short)f_to_bf16u(b[0]); v[5] = (short)f_to_bf16u(b[1]);
        v[6] = (short)f_to_bf16u(b[2]); v[7] = (short)f_to_bf16u(b[3]);
        *(short8*)&Wc[i] = v;
    } else {
        *(short8*)&Wc[i] = *(const short8*)&((const short*)W)[i];
    }
}

// ---------------------------------------------------------------------------
// Kernel 1: GEMM + gate math + fused scan summaries.
// Block 256 = 4 waves (2x2). A staged from original x (dual dtype path,
// fp32 path prefetched one K-step ahead in regs), B staged via
// global_load_lds width-16 from Wc. LDS XOR swizzle (conflicts ~0).
// Tail: wave w scans its 32-t sub-segment -> Asub/Bsub (global) + LDS;
// wave 0 folds 4 -> Asum/Bval.
// Grid (256, 8): by = blockIdx.x so same-by col-blocks share an XCD L2.
// launch_bounds (256,2): ~212 unified regs/wave incl. prefetch; 2 waves/EU.
// ---------------------------------------------------------------------------
__global__ __launch_bounds__(256, 2)
void gemm_gates(const void* __restrict__ x,
                const unsigned short* __restrict__ W,
                const float* __restrict__ bias,
                const int* __restrict__ flag,
                h2* __restrict__ plv,
                float* __restrict__ Asum, float* __restrict__ Bval,
                float* __restrict__ Asub, float* __restrict__ Bsub) {
    __shared__ __align__(16) char ldsbuf[40960];
    short* Alds = (short*)ldsbuf;              // 16 KB during K-loop
    short* Blds = (short*)(ldsbuf + 16384);    // 24 KB during K-loop
    h2* sc = (h2*)ldsbuf;                      // 32 KB after K-loop
    float* sa = (float*)(ldsbuf + 32768);      // 1 KB sub-summary A
    float* sb = sa + 256;                      // 1 KB sub-summary B

    const int by = blockIdx.x;             // row block 0..255 (XCD = by%8)
    const int bx = blockIdx.y;             // col block 0..7 (64 cols/gate)
    const int tid = threadIdx.x;
    const int lane = tid & 63;
    const int w = tid >> 6;
    const int wr = (w >> 1) * 64;
    const int wc2 = w & 1;
    const int l8 = lane >> 3, s8 = lane & 7;
    const int sg = s8 ^ l8;                // swizzled global seg for staging
    const int fr = lane & 15;
    const int q = lane >> 4;

    const int R0 = by * BM;
    const int f32in = *flag;

    floatx4 acc[4][6];
    #pragma unroll
    for (int i = 0; i < 4; i++)
        #pragma unroll
        for (int j = 0; j < 6; j++)
            acc[i][j] = (floatx4){0.f, 0.f, 0.f, 0.f};

    const float* xf = (const float*)x;
    const short* xh = (const short*)x;
    const short* wg = (const short*)W;

    // fp32-A prefetch registers: one K-step (4 chunks x 32B) per thread.
    float4v va[4][2];

    if (f32in) {
        #pragma unroll
        for (int i = 0; i < 4; i++) {
            int c = w * 4 + i;
            const float* g = xf + (size_t)(R0 + c * 8 + l8) * H_DIM + 0 + sg * 8;
            va[i][0] = *(const float4v*)g;
            va[i][1] = *(const float4v*)(g + 4);
        }
    }

    for (int k0 = 0; k0 < H_DIM; k0 += BK) {
        __syncthreads();
        if (f32in) {
            // consume prefetched regs: cvt_pk bf16 -> ds_write_b128.
            // Same LDS image as gload_lds path: dest = chunk base + lane*16B,
            // data = global seg (s8 ^ l8) of row c*8+l8.
            #pragma unroll
            for (int i = 0; i < 4; i++) {
                int c = w * 4 + i;
                union { short8 s; unsigned int u[4]; } pkv;
                pkv.u[0] = cvtpk_bf16(va[i][0][0], va[i][0][1]);
                pkv.u[1] = cvtpk_bf16(va[i][0][2], va[i][0][3]);
                pkv.u[2] = cvtpk_bf16(va[i][1][0], va[i][1][1]);
                pkv.u[3] = cvtpk_bf16(va[i][1][2], va[i][1][3]);
                *(short8*)&Alds[c * 512 + lane * 8] = pkv.s;
            }
        } else {
            #pragma unroll
            for (int i = 0; i < 4; i++) {
                int c = w * 4 + i;
                const short* g = xh + (size_t)(R0 + c * 8 + l8) * H_DIM + k0 + sg * 8;
                gload_lds16(g, &Alds[c * 512]);
            }
        }
        #pragma unroll
        for (int i = 0; i < 6; i++) {
            int c = w * 6 + i;
            int br = c * 8 + l8;
            int wrow = (br >> 6) * H_DIM + bx * 64 + (br & 63);
            const short* g = wg + (size_t)wrow * H_DIM + k0 + sg * 8;
            gload_lds16(g, &Blds[c * 512]);
        }
        __syncthreads();

        // Issue next K-step's A loads now: they have the whole compute
        // phase (+ next barrier wait) to land before the next cvt uses them.
        if (f32in && k0 + BK < H_DIM) {
            const int kn = k0 + BK;
            #pragma unroll
            for (int i = 0; i < 4; i++) {
                int c = w * 4 + i;
                const float* g = xf + (size_t)(R0 + c * 8 + l8) * H_DIM + kn + sg * 8;
                va[i][0] = *(const float4v*)g;
                va[i][1] = *(const float4v*)(g + 4);
            }
        }

        #pragma unroll
        for (int ks = 0; ks < 2; ks++) {
            const int s = ks * 4 + q;
            short8 af[4], bf[6];
            #pragma unroll
            for (int mt = 0; mt < 4; mt++) {
                int ar = wr + mt * 16 + fr;
                af[mt] = *(const short8*)&Alds[ar * BK + ((s ^ (ar & 7)) << 3)];
            }
            #pragma unroll
            for (int j = 0; j < 6; j++) {
                int nt = (j >> 1) * 4 + wc2 * 2 + (j & 1);
                int brr = nt * 16 + fr;
                bf[j] = *(const short8*)&Blds[brr * BK + ((s ^ (brr & 7)) << 3)];
            }
            #pragma unroll
            for (int mt = 0; mt < 4; mt++)
                #pragma unroll
                for (int j = 0; j < 6; j++)
                    acc[mt][j] = __builtin_amdgcn_mfma_f32_16x16x32_bf16(
                        af[mt], bf[j], acc[mt][j], 0, 0, 0);
        }
    }

    __syncthreads();   // staging LDS dead; reuse as sc

    // Epilogue: C/D layout col=lane&15, row=quad*4+reg [m89/m91].
    // sigma-sum form, all in log2 units:
    //   af=1+2^(-f*log2e), ai=1+2^(-i*log2e), s=af+ai
    //   lf = log2(ai)-log2(s); lv = log2(af)-log2(s) + lg
    //   lg = h>=0 ? log2(h+0.5) : -log2(1+2^(-h*log2e))  (argument-select)
    const int rowb = R0 + wr + q * 4;
    const int tloc0 = wr + q * 4;
    #pragma unroll
    for (int jj = 0; jj < 2; jj++) {
        int hl = wc2 * 32 + jj * 16 + fr;
        int hcol = bx * 64 + hl;
        float bfv = bias[hcol];
        float biv = bias[H_DIM + hcol];
        float bhv = bias[2 * H_DIM + hcol];
        float bf2 = -bfv * C_LOG2E;        // fold bias into exp arg via fma
        float bi2 = -biv * C_LOG2E;
        #pragma unroll
        for (int mt = 0; mt < 4; mt++) {
            #pragma unroll
            for (int r = 0; r < 4; r++) {
                float ef = exp2_hw(fminf(fmaf(acc[mt][jj][r], -C_LOG2E, bf2), 126.0f));
                float ei = exp2_hw(fminf(fmaf(acc[mt][2 + jj][r], -C_LOG2E, bi2), 126.0f));
                float hp = acc[mt][4 + jj][r] + bhv;
                float eh = exp2_hw(fminf(-hp * C_LOG2E, 126.0f));
                float afv = 1.0f + ef, aiv = 1.0f + ei;
                float sfi = afv + aiv;
                float ls = log2_hw(sfi);
                float lf = log2_hw(aiv) - ls;                  // log2 f'
                float marg = (hp >= 0.0f) ? (hp + 0.5f) : (1.0f + eh);
                float lm = log2_hw(marg);
                float lg = (hp >= 0.0f) ? lm : -lm;            // log2 g
                float lv = (log2_hw(afv) - ls) + lg;           // log2 (i' g)
                int row = rowb + mt * 16 + r;
                h2 pk;
                pk[0] = (_Float16)lf;
                pk[1] = (_Float16)lv;
                plv[(size_t)row * H_DIM + hcol] = pk;
                sc[(tloc0 + mt * 16 + r) * 64 + hl] = pk;
            }
        }
    }

    __syncthreads();

    const int n = by >> 5, c = by & 31;
    // Wave w scans t in [w*32, w*32+32) for col=lane; publish sub-summary.
    {
        float a = 0.f, bacc = NEG_BIG;
        const int t0 = w * 32;
        #pragma unroll 4
        for (int t = t0; t < t0 + 32; t++) {
            h2 p = sc[t * 64 + lane];
            float f = (float)p[0];
            bacc = logaddexp2_f(f + bacc, (float)p[1]);
            a += f;
        }
        sa[w * 64 + lane] = a;
        sb[w * 64 + lane] = bacc;
        size_t o = (((size_t)n * NC + c) * 4 + w) * H_DIM + bx * 64 + lane;
        Asub[o] = a;
        Bsub[o] = bacc;
    }
    __syncthreads();

    if (w == 0) {
        float a = sa[lane], b = sb[lane];
        #pragma unroll
        for (int s = 1; s < 4; s++) {
            float as = sa[s * 64 + lane], bs = sb[s * 64 + lane];
            b = logaddexp2_f(as + b, bs);
            a += as;
        }
        size_t o = ((size_t)n * NC + c) * H_DIM + bx * 64 + lane;
        Asum[o] = a;
        Bval[o] = b;
    }
}

// ---------------------------------------------------------------------------
// Kernel 2: sub-chunk replay. Block (cc, n): c = cc>>2, s = cc&3.
// Carry = fold of c chunk summaries + s sub-summaries (<=34 steps), then
// replay 32 timesteps. 2 h-cols/thread, 8B loads. grid (128, 8) = 1024 blocks.
// Carry-fold loads batched 4-wide to hide L2 latency on the runtime loop.
// ---------------------------------------------------------------------------
__global__ __launch_bounds__(256)
void scan_apply(const h2* __restrict__ plv,
                const float* __restrict__ Asum, const float* __restrict__ Bval,
                const float* __restrict__ Asub, const float* __restrict__ Bsub,
                void* __restrict__ outv, const int* __restrict__ flag) {
    const int cc = blockIdx.x;          // 0..127
    const int n = blockIdx.y;
    const int c = cc >> 2, s = cc & 3;
    const int h0 = threadIdx.x * 2;
    const int f32out = *flag;

    float r0 = LOG2_HX0;                // log2(1e-6)
    float r1 = r0;
    size_t so = (size_t)n * NC * H_DIM + h0;
    int cp = 0;
    for (; cp + 4 <= c; cp += 4) {
        float2v A0 = *(const float2v*)&Asum[so + (size_t)(cp + 0) * H_DIM];
        float2v B0 = *(const float2v*)&Bval[so + (size_t)(cp + 0) * H_DIM];
        float2v A1 = *(const float2v*)&Asum[so + (size_t)(cp + 1) * H_DIM];
        float2v B1 = *(const float2v*)&Bval[so + (size_t)(cp + 1) * H_DIM];
        float2v A2 = *(const float2v*)&Asum[so + (size_t)(cp + 2) * H_DIM];
        float2v B2 = *(const float2v*)&Bval[so + (size_t)(cp + 2) * H_DIM];
        float2v A3 = *(const float2v*)&Asum[so + (size_t)(cp + 3) * H_DIM];
        float2v B3 = *(const float2v*)&Bval[so + (size_t)(cp + 3) * H_DIM];
        r0 = logaddexp2_f(A0[0] + r0, B0[0]); r1 = logaddexp2_f(A0[1] + r1, B0[1]);
        r0 = logaddexp2_f(A1[0] + r0, B1[0]); r1 = logaddexp2_f(A1[1] + r1, B1[1]);
        r0 = logaddexp2_f(A2[0] + r0, B2[0]); r1 = logaddexp2_f(A2[1] + r1, B2[1]);
        r0 = logaddexp2_f(A3[0] + r0, B3[0]); r1 = logaddexp2_f(A3[1] + r1, B3[1]);
    }
    for (; cp < c; cp++) {
        float2v A = *(const float2v*)&Asum[so + (size_t)cp * H_DIM];
        float2v B = *(const float2v*)&Bval[so + (size_t)cp * H_DIM];
        r0 = logaddexp2_f(A[0] + r0, B[0]);
        r1 = logaddexp2_f(A[1] + r1, B[1]);
    }
    size_t sub = (((size_t)n * NC + c) * 4) * H_DIM + h0;
    for (int sp = 0; sp < s; sp++) {
        float2v A = *(const float2v*)&Asub[sub + (size_t)sp * H_DIM];
        float2v B = *(const float2v*)&Bsub[sub + (size_t)sp * H_DIM];
        r0 = logaddexp2_f(A[0] + r0, B[0]);
        r1 = logaddexp2_f(A[1] + r1, B[1]);
    }

    size_t base = ((size_t)n * LSEQ + (size_t)c * CS + s * 32) * H_DIM + h0;
    if (f32out) {
        float* of = (float*)outv;
        #pragma unroll 4
        for (int t = 0; t < 32; t++) {
            size_t idx = base + (size_t)t * H_DIM;
            h4 p = *(const h4*)&plv[idx];          // (lf0, lv0, lf1, lv1)
            r0 = logaddexp2_f((float)p[0] + r0, (float)p[1]);
            r1 = logaddexp2_f((float)p[2] + r1, (float)p[3]);
            float2v o2 = {exp2_hw(r0), exp2_hw(r1)};
            *(float2v*)&of[idx] = o2;
        }
    } else {
        unsigned int* ob32 = (unsigned int*)outv;
        #pragma unroll 4
        for (int t = 0; t < 32; t++) {
            size_t idx = base + (size_t)t * H_DIM;
            h4 p = *(const h4*)&plv[idx];
            r0 = logaddexp2_f((float)p[0] + r0, (float)p[1]);
            r1 = logaddexp2_f((float)p[2] + r1, (float)p[3]);
            unsigned int pk = ((unsigned int)f_to_bf16u(exp2_hw(r1)) << 16)
                            | f_to_bf16u(exp2_hw(r0));
            ob32[idx >> 1] = pk;
        }
    }
}

extern "C" void kernel_launch(void* const* d_in, const int* in_sizes, int n_in,
                              void* d_out, int out_size, void* d_ws, size_t ws_size,
                              hipStream_t stream) {
    const void* x = d_in[0];
    const void* W = d_in[1];
    const void* b = d_in[2];

    char* wsb = (char*)d_ws;
    int* flag            = (int*)wsb;                          // 16 B
    float* bconv         = (float*)(wsb + 16);                 // 6 KB
    unsigned short* Wc   = (unsigned short*)(wsb + 16384 + 33554432);  // 1.5 MB
    h2* plv              = (h2*)(wsb + 36700160);              // 64 MB packed (lf,lv)
    float* Asum          = (float*)(wsb + 103809024);          // 512 KB
    float* Bval          = (float*)(wsb + 104333312);          // 512 KB
    float* Asub          = (float*)(wsb + 104857600);          // 2 MB
    float* Bsub          = (float*)(wsb + 106954752);          // 2 MB

    detect_and_bias<<<1, 256, 0, stream>>>((const unsigned short*)x, b, flag, bconv);
    convert_w<<<384, 256, 0, stream>>>(W, Wc, flag);

    dim3 g1(M_TOTAL / BM, H_DIM / 64);   // (256, 8): by on x for XCD share
    gemm_gates<<<g1, 256, 0, stream>>>(x, Wc, bconv, flag, plv, Asum, Bval, Asub, Bsub);

    dim3 g2(NC * 4, NBATCH);             // (128, 8)
    scan_apply<<<g2, 256, 0, stream>>>(plv, Asum, Bval, Asub, Bsub, d_out, flag);
}